// Round 10
// baseline (212.433 us; speedup 1.0000x reference)
//
#include <hip/hip_runtime.h>
#include <hip/hip_bf16.h>

constexpr int B_ = 2;
constexpr int T_ = 2048;
constexpr int C_ = 1024;
constexpr int H_ = 16;
constexpr int D_ = 64;
constexpr int M_ = B_ * T_;   // 4096 rows

typedef __attribute__((ext_vector_type(8))) short bf16x8;   // 8 bf16 = 4 VGPRs
typedef __attribute__((ext_vector_type(4))) float f32x4;
typedef const __attribute__((address_space(1))) void gaddr_t;
typedef __attribute__((address_space(3))) void laddr_t;

__device__ __forceinline__ unsigned short f2bf(float f) {   // fp32 -> bf16 RNE
    unsigned u = __float_as_uint(f);
    return (unsigned short)((u + 0x7fffu + ((u >> 16) & 1u)) >> 16);
}

union BF8 { bf16x8 v; __hip_bfloat162 h[4]; };

__device__ __forceinline__ bf16x8 cvt8(const float4 a, const float4 b) {
    BF8 r;
    r.h[0] = __float22bfloat162_rn(make_float2(a.x, a.y));
    r.h[1] = __float22bfloat162_rn(make_float2(a.z, a.w));
    r.h[2] = __float22bfloat162_rn(make_float2(b.x, b.y));
    r.h[3] = __float22bfloat162_rn(make_float2(b.z, b.w));
    return r.v;
}

// ---------------------------------------------------------------------------
// x (fp32) -> xb (bf16), flat
// ---------------------------------------------------------------------------
__global__ __launch_bounds__(256)
void cast_x(const float* __restrict__ x, unsigned short* __restrict__ xb, int n4)
{
    for (int i = blockIdx.x * 256 + threadIdx.x; i < n4; i += gridDim.x * 256) {
        float4 v = ((const float4*)x)[i];
        union { __hip_bfloat162 h[2]; ushort4 u; } o;
        o.h[0] = __float22bfloat162_rn(make_float2(v.x, v.y));
        o.h[1] = __float22bfloat162_rn(make_float2(v.z, v.w));
        ((ushort4*)xb)[i] = o.u;
    }
}

// ---------------------------------------------------------------------------
// W (K x N fp32, row-major) -> Wt (N x K bf16, row-major) for 4 weights.
// ---------------------------------------------------------------------------
__global__ __launch_bounds__(256)
void tcast_w(const float* __restrict__ Wq, const float* __restrict__ Wk,
             const float* __restrict__ Wv, const float* __restrict__ Wo,
             unsigned short* __restrict__ wtb)
{
    __shared__ float tile[64][65];
    const int z = blockIdx.z;
    const float* W = (z == 0) ? Wq : (z == 1) ? Wk : (z == 2) ? Wv : Wo;
    unsigned short* O = wtb + (size_t)z * C_ * C_;

    const int tid = threadIdx.x;
    const int n0 = blockIdx.x * 64, k0 = blockIdx.y * 64;
    const int r = tid >> 4, c4 = (tid & 15) * 4;

#pragma unroll
    for (int i = 0; i < 4; ++i) {
        const int kk = i * 16 + r;
        float4 v = *(const float4*)(W + (size_t)(k0 + kk) * C_ + n0 + c4);
        tile[c4 + 0][kk] = v.x;
        tile[c4 + 1][kk] = v.y;
        tile[c4 + 2][kk] = v.z;
        tile[c4 + 3][kk] = v.w;
    }
    __syncthreads();
#pragma unroll
    for (int i = 0; i < 4; ++i) {
        const int nn = i * 16 + r;
        ushort4 o;
        o.x = f2bf(tile[nn][c4 + 0]);
        o.y = f2bf(tile[nn][c4 + 1]);
        o.z = f2bf(tile[nn][c4 + 2]);
        o.w = f2bf(tile[nn][c4 + 3]);
        *(ushort4*)(O + (size_t)(n0 + nn) * C_ + k0 + c4) = o;
    }
}

// ---------------------------------------------------------------------------
// Fused QKV bf16 MFMA GEMM — BK=64 (16 k-iters, half the barrier drains of
// BK=32; LDS 32 KB). DMA issue de-interleaved: all A chunks, then all B
// chunks (R8-proven ordering). 128x128 tile, global_load_lds w16 staging.
// q -> qb (bf16); k -> kout (fp32) [+ kb bf16 if WRITE_KB]; v -> vout (fp32).
// ---------------------------------------------------------------------------
template<int WRITE_KB>
__global__ __launch_bounds__(256)
void gemm_qkv(const unsigned short* __restrict__ xb, const unsigned short* __restrict__ wtb,
              unsigned short* __restrict__ qb, float* __restrict__ kout,
              float* __restrict__ vout, unsigned short* __restrict__ kb)
{
    __shared__ unsigned short As[128 * 64];   // 16 KB
    __shared__ unsigned short Bs[128 * 64];   // 16 KB

    const int tid = threadIdx.x;
    const int which = blockIdx.x >> 3;             // 0=q 1=k 2=v
    const int n0 = (blockIdx.x & 7) * 128;
    const int m0 = blockIdx.y * 128;
    const unsigned short* wt = wtb + (size_t)which * C_ * C_;

    const int lane = tid & 63, w = tid >> 6;
    const int wm = (w >> 1) * 64, wn = (w & 1) * 64;
    const int fr = lane & 15, qd = lane >> 4;

    f32x4 acc[4][4] = {};

    for (int k0 = 0; k0 < C_; k0 += 64) {
        // chunk c of 1024: row = c>>3, k8 = (c&7)*8; LDS byte off = c*16
#pragma unroll
        for (int cc = 0; cc < 4; ++cc) {
            const int c = tid + cc * 256;
            __builtin_amdgcn_global_load_lds(
                (gaddr_t*)(xb + (size_t)(m0 + (c >> 3)) * C_ + k0 + (c & 7) * 8),
                (laddr_t*)((char*)As + (size_t)c * 16), 16, 0, 0);
        }
#pragma unroll
        for (int cc = 0; cc < 4; ++cc) {
            const int c = tid + cc * 256;
            __builtin_amdgcn_global_load_lds(
                (gaddr_t*)(wt + (size_t)(n0 + (c >> 3)) * C_ + k0 + (c & 7) * 8),
                (laddr_t*)((char*)Bs + (size_t)c * 16), 16, 0, 0);
        }
        __syncthreads();

#pragma unroll
        for (int half = 0; half < 2; ++half) {
            bf16x8 af[4], bfv[4];
#pragma unroll
            for (int mt = 0; mt < 4; ++mt)
                af[mt] = *(const bf16x8*)&As[(wm + mt * 16 + fr) * 64 + half * 32 + qd * 8];
#pragma unroll
            for (int nt = 0; nt < 4; ++nt)
                bfv[nt] = *(const bf16x8*)&Bs[(wn + nt * 16 + fr) * 64 + half * 32 + qd * 8];
#pragma unroll
            for (int mt = 0; mt < 4; ++mt)
#pragma unroll
                for (int nt = 0; nt < 4; ++nt)
                    acc[mt][nt] = __builtin_amdgcn_mfma_f32_16x16x32_bf16(
                        af[mt], bfv[nt], acc[mt][nt], 0, 0, 0);
        }
        __syncthreads();
    }

    // C/D layout: col = lane&15, row = (lane>>4)*4 + reg
#pragma unroll
    for (int mt = 0; mt < 4; ++mt) {
#pragma unroll
        for (int nt = 0; nt < 4; ++nt) {
            const int ncol = n0 + wn + nt * 16 + fr;
            const int h = ncol >> 6, d = ncol & 63;
#pragma unroll
            for (int r = 0; r < 4; ++r) {
                const int mm = m0 + wm + mt * 16 + qd * 4 + r;
                const int b = mm >> 11, t = mm & (T_ - 1);
                const int bh = b * H_ + h;
                const size_t off = ((size_t)bh * T_ + t) * D_ + d;
                const float val = acc[mt][nt][r];
                if (which == 0)      qb[off]   = f2bf(val);
                else if (which == 1) {
                    kout[off] = val;
                    if (WRITE_KB) kb[off] = f2bf(val);
                } else               vout[off] = val;
            }
        }
    }
}

// ---------------------------------------------------------------------------
// vout (B,H,T,D fp32) -> vtt (bf16, TILE-CONTIGUOUS V^T):
// layout (B*H, T/64, D, 64): tile (bh,tt) is a contiguous 64x64 [d][t] block.
// ---------------------------------------------------------------------------
__global__ __launch_bounds__(256)
void transpose_v(const float* __restrict__ v, unsigned short* __restrict__ vtt)
{
    __shared__ unsigned short tile[64 * 66];
    const int tid = threadIdx.x;
    const int bh = blockIdx.y, t0 = blockIdx.x * 64;
    const float* vB = v + ((size_t)bh * T_ + t0) * D_;

    const int r = tid >> 4, c4 = (tid & 15) * 4;
#pragma unroll
    for (int i = 0; i < 4; ++i) {
        const int tt = i * 16 + r;
        float4 x4 = *(const float4*)(vB + tt * D_ + c4);
        tile[(c4 + 0) * 66 + tt] = f2bf(x4.x);
        tile[(c4 + 1) * 66 + tt] = f2bf(x4.y);
        tile[(c4 + 2) * 66 + tt] = f2bf(x4.z);
        tile[(c4 + 3) * 66 + tt] = f2bf(x4.w);
    }
    __syncthreads();
    unsigned short* out = vtt + (((size_t)bh * (T_ / 64) + (t0 >> 6)) * 64) * 64;
#pragma unroll
    for (int i = 0; i < 4; ++i) {
        const int d = i * 16 + r;
        ushort4 o;
        o.x = tile[d * 66 + c4 + 0];
        o.y = tile[d * 66 + c4 + 1];
        o.z = tile[d * 66 + c4 + 2];
        o.w = tile[d * 66 + c4 + 3];
        *(ushort4*)(out + d * 64 + c4) = o;
    }
}

// ---------------------------------------------------------------------------
// Output projection: out = attb @ Wo + bo (bf16 MFMA, fp32 out) — BK=64.
// ---------------------------------------------------------------------------
__global__ __launch_bounds__(256)
void gemm_o(const unsigned short* __restrict__ ab, const unsigned short* __restrict__ wot,
            const float* __restrict__ bo, float* __restrict__ out)
{
    __shared__ unsigned short As[128 * 64];
    __shared__ unsigned short Bs[128 * 64];

    const int tid = threadIdx.x;
    const int n0 = blockIdx.x * 128;
    const int m0 = blockIdx.y * 128;

    const int lane = tid & 63, w = tid >> 6;
    const int wm = (w >> 1) * 64, wn = (w & 1) * 64;
    const int fr = lane & 15, qd = lane >> 4;

    f32x4 acc[4][4] = {};

    for (int k0 = 0; k0 < C_; k0 += 64) {
#pragma unroll
        for (int cc = 0; cc < 4; ++cc) {
            const int c = tid + cc * 256;
            __builtin_amdgcn_global_load_lds(
                (gaddr_t*)(ab + (size_t)(m0 + (c >> 3)) * C_ + k0 + (c & 7) * 8),
                (laddr_t*)((char*)As + (size_t)c * 16), 16, 0, 0);
        }
#pragma unroll
        for (int cc = 0; cc < 4; ++cc) {
            const int c = tid + cc * 256;
            __builtin_amdgcn_global_load_lds(
                (gaddr_t*)(wot + (size_t)(n0 + (c >> 3)) * C_ + k0 + (c & 7) * 8),
                (laddr_t*)((char*)Bs + (size_t)c * 16), 16, 0, 0);
        }
        __syncthreads();

#pragma unroll
        for (int half = 0; half < 2; ++half) {
            bf16x8 af[4], bfv[4];
#pragma unroll
            for (int mt = 0; mt < 4; ++mt)
                af[mt] = *(const bf16x8*)&As[(wm + mt * 16 + fr) * 64 + half * 32 + qd * 8];
#pragma unroll
            for (int nt = 0; nt < 4; ++nt)
                bfv[nt] = *(const bf16x8*)&Bs[(wn + nt * 16 + fr) * 64 + half * 32 + qd * 8];
#pragma unroll
            for (int mt = 0; mt < 4; ++mt)
#pragma unroll
                for (int nt = 0; nt < 4; ++nt)
                    acc[mt][nt] = __builtin_amdgcn_mfma_f32_16x16x32_bf16(
                        af[mt], bfv[nt], acc[mt][nt], 0, 0, 0);
        }
        __syncthreads();
    }

#pragma unroll
    for (int mt = 0; mt < 4; ++mt) {
#pragma unroll
        for (int nt = 0; nt < 4; ++nt) {
            const int ncol = n0 + wn + nt * 16 + fr;
            const float bb = bo[ncol];
#pragma unroll
            for (int r = 0; r < 4; ++r) {
                const int mm = m0 + wm + mt * 16 + qd * 4 + r;
                out[(size_t)mm * C_ + ncol] = acc[mt][nt][r] + bb;
            }
        }
    }
}

// ---------------------------------------------------------------------------
// MFMA flash attention v5 — LDS-shared K/V tiles (unchanged from R8-passing).
// ---------------------------------------------------------------------------
__global__ __launch_bounds__(256)
void attn_lds(const unsigned short* __restrict__ qb, const unsigned short* __restrict__ kb,
              const unsigned short* __restrict__ vtt, unsigned short* __restrict__ attb)
{
    __shared__ unsigned short Ks[64 * 64];
    __shared__ unsigned short Vs[64 * 64];
    __shared__ alignas(16) unsigned short Pt[4][16 * 72];

    const int tid = threadIdx.x;
    const int lane = tid & 63, w = tid >> 6;
    const int fr = lane & 15, qd = lane >> 4;

    const int blk = blockIdx.x;
    const int xcd = blk & 7, within = blk >> 3;      // within: 0..127
    const int bh = xcd * 4 + (within & 3);           // bh constant per CU slot
    const int jj = within >> 2;                      // 0..31
    const int kk_ = jj >> 3, ii_ = jj & 7;
    const int qt = (kk_ == 0) ? (31 - ii_) : (kk_ == 1) ? ii_
                 : (kk_ == 2) ? (23 - ii_) : (8 + ii_);
    const int b = bh >> 4, h = bh & 15;

    unsigned short* Pw = Pt[w];
    const unsigned short* qB = qb  + (size_t)bh * T_ * D_;
    const unsigned short* kB = kb  + (size_t)bh * T_ * D_;
    const unsigned short* vT = vtt + (size_t)bh * (T_ / 64) * 64 * 64;

    const int qr0 = qt * 64 + w * 16;
    const int qrow_g = qr0 + fr;

    bf16x8 aq0 = *(const bf16x8*)(qB + (size_t)(qr0 + fr) * D_ + qd * 8);
    bf16x8 aq1 = *(const bf16x8*)(qB + (size_t)(qr0 + fr) * D_ + 32 + qd * 8);

    f32x4 accT[4] = {};
    float l_i = 0.0f;
    const float sc2 = 0.18033688f;                   // log2(e) / sqrt(64)

    const int L0 = w * 128 + lane, L1 = L0 + 64;
    const int r0 = L0 >> 3, e0 = (((L0 & 7) ^ (r0 & 7)) * 8);
    const int r1 = L1 >> 3, e1 = (((L1 & 7) ^ (r1 & 7)) * 8);
    laddr_t* dK0 = (laddr_t*)((char*)Ks + (size_t)L0 * 16);
    laddr_t* dK1 = (laddr_t*)((char*)Ks + (size_t)L1 * 16);
    laddr_t* dV0 = (laddr_t*)((char*)Vs + (size_t)L0 * 16);
    laddr_t* dV1 = (laddr_t*)((char*)Vs + (size_t)L1 * 16);

    for (int jt = 0; jt <= qt; ++jt) {
        __syncthreads();
        {
            const unsigned short* kt = kB + (size_t)(jt * 64) * 64;
            const unsigned short* vt = vT + (size_t)jt * 4096;
            __builtin_amdgcn_global_load_lds((gaddr_t*)(kt + r0 * 64 + e0), dK0, 16, 0, 0);
            __builtin_amdgcn_global_load_lds((gaddr_t*)(kt + r1 * 64 + e1), dK1, 16, 0, 0);
            __builtin_amdgcn_global_load_lds((gaddr_t*)(vt + r0 * 64 + e0), dV0, 16, 0, 0);
            __builtin_amdgcn_global_load_lds((gaddr_t*)(vt + r1 * 64 + e1), dV1, 16, 0, 0);
        }
        __syncthreads();

        bf16x8 bk[8];
#pragma unroll
        for (int q8 = 0; q8 < 8; ++q8) {
            const int row = (q8 >> 1) * 16 + fr;
            const int dg = (q8 & 1) * 4 + qd;
            bk[q8] = *(const bf16x8*)&Ks[row * 64 + ((dg ^ (row & 7)) * 8)];
        }

        f32x4 s4[4] = {};
#pragma unroll
        for (int nt = 0; nt < 4; ++nt) {
            s4[nt] = __builtin_amdgcn_mfma_f32_16x16x32_bf16(bk[nt * 2 + 0], aq0, s4[nt], 0, 0, 0);
            s4[nt] = __builtin_amdgcn_mfma_f32_16x16x32_bf16(bk[nt * 2 + 1], aq1, s4[nt], 0, 0, 0);
        }

        if (jt == qt) {
            const int kbase = jt * 64 + qd * 4;
#pragma unroll
            for (int nt = 0; nt < 4; ++nt)
#pragma unroll
            for (int r = 0; r < 4; ++r) {
                const int kcol = kbase + nt * 16 + r;
                const float pv = (kcol <= qrow_g)
                               ? __builtin_amdgcn_exp2f(s4[nt][r] * sc2) : 0.0f;
                s4[nt][r] = pv;
                l_i += pv;
            }
        } else {
#pragma unroll
            for (int nt = 0; nt < 4; ++nt)
#pragma unroll
            for (int r = 0; r < 4; ++r) {
                const float pv = __builtin_amdgcn_exp2f(s4[nt][r] * sc2);
                s4[nt][r] = pv;
                l_i += pv;
            }
        }

#pragma unroll
        for (int nt = 0; nt < 4; ++nt) {
            union { __hip_bfloat162 h2[2]; unsigned long long u; } pk;
            pk.h2[0] = __float22bfloat162_rn(make_float2(s4[nt][0], s4[nt][1]));
            pk.h2[1] = __float22bfloat162_rn(make_float2(s4[nt][2], s4[nt][3]));
            *(unsigned long long*)&Pw[fr * 72 + nt * 16 + qd * 4] = pk.u;
        }
        const bf16x8 ap0 = *(const bf16x8*)&Pw[fr * 72 + qd * 8];
        const bf16x8 ap1 = *(const bf16x8*)&Pw[fr * 72 + 32 + qd * 8];

        bf16x8 bv[8];
#pragma unroll
        for (int q8 = 0; q8 < 8; ++q8) {
            const int row = (q8 >> 1) * 16 + fr;
            const int dg = (q8 & 1) * 4 + qd;
            bv[q8] = *(const bf16x8*)&Vs[row * 64 + ((dg ^ (row & 7)) * 8)];
        }

#pragma unroll
        for (int nt = 0; nt < 4; ++nt) {
            accT[nt] = __builtin_amdgcn_mfma_f32_16x16x32_bf16(bv[nt * 2 + 0], ap0, accT[nt], 0, 0, 0);
            accT[nt] = __builtin_amdgcn_mfma_f32_16x16x32_bf16(bv[nt * 2 + 1], ap1, accT[nt], 0, 0, 0);
        }
    }

    l_i += __shfl_xor(l_i, 16);
    l_i += __shfl_xor(l_i, 32);
    const float inv = 1.0f / l_i;

#pragma unroll
    for (int nt = 0; nt < 4; ++nt) {
        union { __hip_bfloat162 h2[2]; unsigned long long u; } ok;
        ok.h2[0] = __float22bfloat162_rn(make_float2(accT[nt][0] * inv, accT[nt][1] * inv));
        ok.h2[1] = __float22bfloat162_rn(make_float2(accT[nt][2] * inv, accT[nt][3] * inv));
        *(unsigned long long*)&Pw[fr * 72 + nt * 16 + qd * 4] = ok.u;
    }
    {
        const int row = lane >> 2, d0 = (lane & 3) * 16;
        const bf16x8 o0 = *(const bf16x8*)&Pw[row * 72 + d0];
        const bf16x8 o1 = *(const bf16x8*)&Pw[row * 72 + d0 + 8];
        unsigned short* op = attb + ((size_t)b * T_ + qr0 + row) * C_ + h * 64 + d0;
        *(bf16x8*)op = o0;
        *(bf16x8*)(op + 8) = o1;
    }
}

// ---------------------------------------------------------------------------
// Fallback (ws too small for kb): per-wave kernel, fp32 K + tiled V^T.
// ---------------------------------------------------------------------------
__global__ __launch_bounds__(256)
void attn_v4(const unsigned short* __restrict__ qb, const float* __restrict__ kf,
             const unsigned short* __restrict__ vtt, unsigned short* __restrict__ attb)
{
    __shared__ alignas(16) unsigned short Pt[4][16 * 72];

    const int tid = threadIdx.x;
    const int lane = tid & 63, w = tid >> 6;
    const int fr = lane & 15, qd = lane >> 4;

    const int blk = blockIdx.x;
    const int xcd = blk & 7, within = blk >> 3;
    const int bh = xcd * 4 + (within & 3);
    const int jj = within >> 2;
    const int kk_ = jj >> 3, ii_ = jj & 7;
    const int qt = (kk_ == 0) ? (31 - ii_) : (kk_ == 1) ? ii_
                 : (kk_ == 2) ? (23 - ii_) : (8 + ii_);
    const int b = bh >> 4, h = bh & 15;

    unsigned short* Pw = Pt[w];
    const unsigned short* qB = qb  + (size_t)bh * T_ * D_;
    const float*          kB = kf  + (size_t)bh * T_ * D_;
    const unsigned short* vT = vtt + (size_t)bh * (T_ / 64) * 64 * 64;

    const int qr0 = qt * 64 + w * 16;
    const int qrow_g = qr0 + fr;

    bf16x8 aq0 = *(const bf16x8*)(qB + (size_t)(qr0 + fr) * D_ + qd * 8);
    bf16x8 aq1 = *(const bf16x8*)(qB + (size_t)(qr0 + fr) * D_ + 32 + qd * 8);

    f32x4 accT[4] = {};
    float l_i = 0.0f;
    const float sc2 = 0.18033688f;

    for (int jt = 0; jt <= qt; ++jt) {
        bf16x8 bk[8];
#pragma unroll
        for (int q8 = 0; q8 < 8; ++q8) {
            const float* p = kB + (size_t)(jt * 64 + (q8 >> 1) * 16 + fr) * D_
                           + (q8 & 1) * 32 + qd * 8;
            bk[q8] = cvt8(*(const float4*)p, *(const float4*)(p + 4));
        }
        f32x4 s4[4] = {};
#pragma unroll
        for (int nt = 0; nt < 4; ++nt) {
            s4[nt] = __builtin_amdgcn_mfma_f32_16x16x32_bf16(bk[nt * 2 + 0], aq0, s4[nt], 0, 0, 0);
            s4[nt] = __builtin_amdgcn_mfma_f32_16x16x32_bf16(bk[nt * 2 + 1], aq1, s4[nt], 0, 0, 0);
        }
        if (jt == qt) {
            const int kbase = jt * 64 + qd * 4;
#pragma unroll
            for (int nt = 0; nt < 4; ++nt)
#pragma unroll
            for (int r = 0; r < 4; ++r) {
                const int kcol = kbase + nt * 16 + r;
                const float pv = (kcol <= qrow_g)
                               ? __builtin_amdgcn_exp2f(s4[nt][r] * sc2) : 0.0f;
                s4[nt][r] = pv; l_i += pv;
            }
        } else {
#pragma unroll
            for (int nt = 0; nt < 4; ++nt)
#pragma unroll
            for (int r = 0; r < 4; ++r) {
                const float pv = __builtin_amdgcn_exp2f(s4[nt][r] * sc2);
                s4[nt][r] = pv; l_i += pv;
            }
        }
#pragma unroll
        for (int nt = 0; nt < 4; ++nt) {
            union { __hip_bfloat162 h2[2]; unsigned long long u; } pk;
            pk.h2[0] = __float22bfloat162_rn(make_float2(s4[nt][0], s4[nt][1]));
            pk.h2[1] = __float22bfloat162_rn(make_float2(s4[nt][2], s4[nt][3]));
            *(unsigned long long*)&Pw[fr * 72 + nt * 16 + qd * 4] = pk.u;
        }
        const bf16x8 ap0 = *(const bf16x8*)&Pw[fr * 72 + qd * 8];
        const bf16x8 ap1 = *(const bf16x8*)&Pw[fr * 72 + 32 + qd * 8];

        bf16x8 bv[8];
#pragma unroll
        for (int q8 = 0; q8 < 8; ++q8)
            bv[q8] = *(const bf16x8*)(vT + (size_t)jt * 4096
                                      + ((q8 >> 1) * 16 + fr) * 64 + (q8 & 1) * 32 + qd * 8);
#pragma unroll
        for (int nt = 0; nt < 4; ++nt) {
            accT[nt] = __builtin_amdgcn_mfma_f32_16x16x32_bf16(bv[nt * 2 + 0], ap0, accT[nt], 0, 0, 0);
            accT[nt] = __builtin_amdgcn_mfma_f32_16x16x32_bf16(bv[nt * 2 + 1], ap1, accT[nt], 0, 0, 0);
        }
    }

    l_i += __shfl_xor(l_i, 16);
    l_i += __shfl_xor(l_i, 32);
    const float inv = 1.0f / l_i;
#pragma unroll
    for (int nt = 0; nt < 4; ++nt) {
        union { __hip_bfloat162 h2[2]; unsigned long long u; } ok;
        ok.h2[0] = __float22bfloat162_rn(make_float2(accT[nt][0] * inv, accT[nt][1] * inv));
        ok.h2[1] = __float22bfloat162_rn(make_float2(accT[nt][2] * inv, accT[nt][3] * inv));
        *(unsigned long long*)&Pw[fr * 72 + nt * 16 + qd * 4] = ok.u;
    }
    {
        const int row = lane >> 2, d0 = (lane & 3) * 16;
        const bf16x8 o0 = *(const bf16x8*)&Pw[row * 72 + d0];
        const bf16x8 o1 = *(const bf16x8*)&Pw[row * 72 + d0 + 8];
        unsigned short* op = attb + ((size_t)b * T_ + qr0 + row) * C_ + h * 64 + d0;
        *(bf16x8*)op = o0;
        *(bf16x8*)(op + 8) = o1;
    }
}

// ---------------------------------------------------------------------------
extern "C" void kernel_launch(void* const* d_in, const int* in_sizes, int n_in,
                              void* d_out, int out_size, void* d_ws, size_t ws_size,
                              hipStream_t stream)
{
    (void)in_sizes; (void)n_in; (void)out_size;
    const float* x  = (const float*)d_in[0];
    const float* Wq = (const float*)d_in[1];
    const float* Wk = (const float*)d_in[2];
    const float* Wv = (const float*)d_in[3];
    const float* Wo = (const float*)d_in[4];
    const float* bo = (const float*)d_in[5];

    float* out  = (float*)d_out;                       // (B,T,C)
    float* kout = out  + (size_t)M_ * C_;              // (B,H,T,D) fp32
    float* vout = kout + (size_t)B_ * H_ * T_ * D_;    // (B,H,T,D) fp32

    // ws: xb(8M) | wtb(8M) | qb(8M) | vtt(8M) | kb(8M, optional); attb aliases xb
    unsigned short* xb   = (unsigned short*)d_ws;
    unsigned short* wtb  = xb  + (size_t)M_ * C_;
    unsigned short* qb   = wtb + (size_t)4 * C_ * C_;
    unsigned short* vtt  = qb  + (size_t)M_ * C_;
    unsigned short* kb   = vtt + (size_t)M_ * C_;
    unsigned short* attb = xb;
    const bool use_kb = ws_size >= (size_t)40 * 1024 * 1024;

    cast_x<<<1024, 256, 0, stream>>>(x, xb, (M_ * C_) / 4);
    tcast_w<<<dim3(16, 16, 4), 256, 0, stream>>>(Wq, Wk, Wv, Wo, wtb);

    if (use_kb)
        gemm_qkv<1><<<dim3(24, M_ / 128), 256, 0, stream>>>(xb, wtb, qb, kout, vout, kb);
    else
        gemm_qkv<0><<<dim3(24, M_ / 128), 256, 0, stream>>>(xb, wtb, qb, kout, vout, kb);

    transpose_v<<<dim3(T_ / 64, B_ * H_), 256, 0, stream>>>(vout, vtt);

    if (use_kb)
        attn_lds<<<1024, 256, 0, stream>>>(qb, kb, vtt, attb);
    else
        attn_v4<<<1024, 256, 0, stream>>>(qb, kout, vtt, attb);

    gemm_o<<<dim3(8, M_ / 128), 256, 0, stream>>>(attb, wtb + (size_t)3 * C_ * C_, bo, out);
}

// Round 11
// 202.306 us; speedup vs baseline: 1.0501x; 1.0501x over previous
//
#include <hip/hip_runtime.h>
#include <hip/hip_bf16.h>

constexpr int B_ = 2;
constexpr int T_ = 2048;
constexpr int C_ = 1024;
constexpr int H_ = 16;
constexpr int D_ = 64;
constexpr int M_ = B_ * T_;   // 4096 rows

typedef __attribute__((ext_vector_type(8))) short bf16x8;   // 8 bf16 = 4 VGPRs
typedef __attribute__((ext_vector_type(4))) float f32x4;
typedef const __attribute__((address_space(1))) void gaddr_t;
typedef __attribute__((address_space(3))) void laddr_t;

__device__ __forceinline__ unsigned short f2bf(float f) {   // fp32 -> bf16 RNE
    unsigned u = __float_as_uint(f);
    return (unsigned short)((u + 0x7fffu + ((u >> 16) & 1u)) >> 16);
}

union BF8 { bf16x8 v; __hip_bfloat162 h[4]; };

__device__ __forceinline__ bf16x8 cvt8(const float4 a, const float4 b) {
    BF8 r;
    r.h[0] = __float22bfloat162_rn(make_float2(a.x, a.y));
    r.h[1] = __float22bfloat162_rn(make_float2(a.z, a.w));
    r.h[2] = __float22bfloat162_rn(make_float2(b.x, b.y));
    r.h[3] = __float22bfloat162_rn(make_float2(b.z, b.w));
    return r.v;
}

// ---------------------------------------------------------------------------
// x (fp32) -> xb (bf16), flat
// ---------------------------------------------------------------------------
__global__ __launch_bounds__(256)
void cast_x(const float* __restrict__ x, unsigned short* __restrict__ xb, int n4)
{
    for (int i = blockIdx.x * 256 + threadIdx.x; i < n4; i += gridDim.x * 256) {
        float4 v = ((const float4*)x)[i];
        union { __hip_bfloat162 h[2]; ushort4 u; } o;
        o.h[0] = __float22bfloat162_rn(make_float2(v.x, v.y));
        o.h[1] = __float22bfloat162_rn(make_float2(v.z, v.w));
        ((ushort4*)xb)[i] = o.u;
    }
}

// ---------------------------------------------------------------------------
// W (K x N fp32, row-major) -> Wt (N x K bf16, row-major) for 4 weights.
// ---------------------------------------------------------------------------
__global__ __launch_bounds__(256)
void tcast_w(const float* __restrict__ Wq, const float* __restrict__ Wk,
             const float* __restrict__ Wv, const float* __restrict__ Wo,
             unsigned short* __restrict__ wtb)
{
    __shared__ float tile[64][65];
    const int z = blockIdx.z;
    const float* W = (z == 0) ? Wq : (z == 1) ? Wk : (z == 2) ? Wv : Wo;
    unsigned short* O = wtb + (size_t)z * C_ * C_;

    const int tid = threadIdx.x;
    const int n0 = blockIdx.x * 64, k0 = blockIdx.y * 64;
    const int r = tid >> 4, c4 = (tid & 15) * 4;

#pragma unroll
    for (int i = 0; i < 4; ++i) {
        const int kk = i * 16 + r;
        float4 v = *(const float4*)(W + (size_t)(k0 + kk) * C_ + n0 + c4);
        tile[c4 + 0][kk] = v.x;
        tile[c4 + 1][kk] = v.y;
        tile[c4 + 2][kk] = v.z;
        tile[c4 + 3][kk] = v.w;
    }
    __syncthreads();
#pragma unroll
    for (int i = 0; i < 4; ++i) {
        const int nn = i * 16 + r;
        ushort4 o;
        o.x = f2bf(tile[nn][c4 + 0]);
        o.y = f2bf(tile[nn][c4 + 1]);
        o.z = f2bf(tile[nn][c4 + 2]);
        o.w = f2bf(tile[nn][c4 + 3]);
        *(ushort4*)(O + (size_t)(n0 + nn) * C_ + k0 + c4) = o;
    }
}

// ---------------------------------------------------------------------------
// Fused QKV bf16 MFMA GEMM — BK=64 + XOR-swizzled LDS (kills the 16-way
// bank conflicts the 128 B row stride caused in R10: chunk (row,dg) lives at
// LDS chunk row*8 + (dg^(row&7)); frag reads then spread 2 lanes/bank).
// 128x128 tile, global_load_lds w16 staging, de-interleaved A-then-B issue.
// q -> qb (bf16); k -> kout (fp32) [+ kb bf16 if WRITE_KB]; v -> vout (fp32).
// ---------------------------------------------------------------------------
template<int WRITE_KB>
__global__ __launch_bounds__(256)
void gemm_qkv(const unsigned short* __restrict__ xb, const unsigned short* __restrict__ wtb,
              unsigned short* __restrict__ qb, float* __restrict__ kout,
              float* __restrict__ vout, unsigned short* __restrict__ kb)
{
    __shared__ unsigned short As[128 * 64];   // 16 KB
    __shared__ unsigned short Bs[128 * 64];   // 16 KB

    const int tid = threadIdx.x;
    const int which = blockIdx.x >> 3;             // 0=q 1=k 2=v
    const int n0 = (blockIdx.x & 7) * 128;
    const int m0 = blockIdx.y * 128;
    const unsigned short* wt = wtb + (size_t)which * C_ * C_;

    const int lane = tid & 63, w = tid >> 6;
    const int wm = (w >> 1) * 64, wn = (w & 1) * 64;
    const int fr = lane & 15, qd = lane >> 4;

    f32x4 acc[4][4] = {};

    for (int k0 = 0; k0 < C_; k0 += 64) {
        // LDS chunk c holds global chunk (row = c>>3, dg = (c&7)^(row&7))
#pragma unroll
        for (int cc = 0; cc < 4; ++cc) {
            const int c = tid + cc * 256;
            const int row = c >> 3, dg = (c & 7) ^ (row & 7);
            __builtin_amdgcn_global_load_lds(
                (gaddr_t*)(xb + (size_t)(m0 + row) * C_ + k0 + dg * 8),
                (laddr_t*)((char*)As + (size_t)c * 16), 16, 0, 0);
        }
#pragma unroll
        for (int cc = 0; cc < 4; ++cc) {
            const int c = tid + cc * 256;
            const int row = c >> 3, dg = (c & 7) ^ (row & 7);
            __builtin_amdgcn_global_load_lds(
                (gaddr_t*)(wt + (size_t)(n0 + row) * C_ + k0 + dg * 8),
                (laddr_t*)((char*)Bs + (size_t)c * 16), 16, 0, 0);
        }
        __syncthreads();

#pragma unroll
        for (int half = 0; half < 2; ++half) {
            bf16x8 af[4], bfv[4];
#pragma unroll
            for (int mt = 0; mt < 4; ++mt) {
                const int row = wm + mt * 16 + fr, dg = half * 4 + qd;
                af[mt] = *(const bf16x8*)&As[row * 64 + ((dg ^ (row & 7)) * 8)];
            }
#pragma unroll
            for (int nt = 0; nt < 4; ++nt) {
                const int row = wn + nt * 16 + fr, dg = half * 4 + qd;
                bfv[nt] = *(const bf16x8*)&Bs[row * 64 + ((dg ^ (row & 7)) * 8)];
            }
#pragma unroll
            for (int mt = 0; mt < 4; ++mt)
#pragma unroll
                for (int nt = 0; nt < 4; ++nt)
                    acc[mt][nt] = __builtin_amdgcn_mfma_f32_16x16x32_bf16(
                        af[mt], bfv[nt], acc[mt][nt], 0, 0, 0);
        }
        __syncthreads();
    }

    // C/D layout: col = lane&15, row = (lane>>4)*4 + reg
#pragma unroll
    for (int mt = 0; mt < 4; ++mt) {
#pragma unroll
        for (int nt = 0; nt < 4; ++nt) {
            const int ncol = n0 + wn + nt * 16 + fr;
            const int h = ncol >> 6, d = ncol & 63;
#pragma unroll
            for (int r = 0; r < 4; ++r) {
                const int mm = m0 + wm + mt * 16 + qd * 4 + r;
                const int b = mm >> 11, t = mm & (T_ - 1);
                const int bh = b * H_ + h;
                const size_t off = ((size_t)bh * T_ + t) * D_ + d;
                const float val = acc[mt][nt][r];
                if (which == 0)      qb[off]   = f2bf(val);
                else if (which == 1) {
                    kout[off] = val;
                    if (WRITE_KB) kb[off] = f2bf(val);
                } else               vout[off] = val;
            }
        }
    }
}

// ---------------------------------------------------------------------------
// vout (B,H,T,D fp32) -> vtt (bf16, TILE-CONTIGUOUS V^T):
// layout (B*H, T/64, D, 64): tile (bh,tt) is a contiguous 64x64 [d][t] block.
// ---------------------------------------------------------------------------
__global__ __launch_bounds__(256)
void transpose_v(const float* __restrict__ v, unsigned short* __restrict__ vtt)
{
    __shared__ unsigned short tile[64 * 66];
    const int tid = threadIdx.x;
    const int bh = blockIdx.y, t0 = blockIdx.x * 64;
    const float* vB = v + ((size_t)bh * T_ + t0) * D_;

    const int r = tid >> 4, c4 = (tid & 15) * 4;
#pragma unroll
    for (int i = 0; i < 4; ++i) {
        const int tt = i * 16 + r;
        float4 x4 = *(const float4*)(vB + tt * D_ + c4);
        tile[(c4 + 0) * 66 + tt] = f2bf(x4.x);
        tile[(c4 + 1) * 66 + tt] = f2bf(x4.y);
        tile[(c4 + 2) * 66 + tt] = f2bf(x4.z);
        tile[(c4 + 3) * 66 + tt] = f2bf(x4.w);
    }
    __syncthreads();
    unsigned short* out = vtt + (((size_t)bh * (T_ / 64) + (t0 >> 6)) * 64) * 64;
#pragma unroll
    for (int i = 0; i < 4; ++i) {
        const int d = i * 16 + r;
        ushort4 o;
        o.x = tile[d * 66 + c4 + 0];
        o.y = tile[d * 66 + c4 + 1];
        o.z = tile[d * 66 + c4 + 2];
        o.w = tile[d * 66 + c4 + 3];
        *(ushort4*)(out + d * 64 + c4) = o;
    }
}

// ---------------------------------------------------------------------------
// Output projection: out = attb @ Wo + bo — BK=64 + XOR-swizzled LDS.
// ---------------------------------------------------------------------------
__global__ __launch_bounds__(256)
void gemm_o(const unsigned short* __restrict__ ab, const unsigned short* __restrict__ wot,
            const float* __restrict__ bo, float* __restrict__ out)
{
    __shared__ unsigned short As[128 * 64];
    __shared__ unsigned short Bs[128 * 64];

    const int tid = threadIdx.x;
    const int n0 = blockIdx.x * 128;
    const int m0 = blockIdx.y * 128;

    const int lane = tid & 63, w = tid >> 6;
    const int wm = (w >> 1) * 64, wn = (w & 1) * 64;
    const int fr = lane & 15, qd = lane >> 4;

    f32x4 acc[4][4] = {};

    for (int k0 = 0; k0 < C_; k0 += 64) {
#pragma unroll
        for (int cc = 0; cc < 4; ++cc) {
            const int c = tid + cc * 256;
            const int row = c >> 3, dg = (c & 7) ^ (row & 7);
            __builtin_amdgcn_global_load_lds(
                (gaddr_t*)(ab + (size_t)(m0 + row) * C_ + k0 + dg * 8),
                (laddr_t*)((char*)As + (size_t)c * 16), 16, 0, 0);
        }
#pragma unroll
        for (int cc = 0; cc < 4; ++cc) {
            const int c = tid + cc * 256;
            const int row = c >> 3, dg = (c & 7) ^ (row & 7);
            __builtin_amdgcn_global_load_lds(
                (gaddr_t*)(wot + (size_t)(n0 + row) * C_ + k0 + dg * 8),
                (laddr_t*)((char*)Bs + (size_t)c * 16), 16, 0, 0);
        }
        __syncthreads();

#pragma unroll
        for (int half = 0; half < 2; ++half) {
            bf16x8 af[4], bfv[4];
#pragma unroll
            for (int mt = 0; mt < 4; ++mt) {
                const int row = wm + mt * 16 + fr, dg = half * 4 + qd;
                af[mt] = *(const bf16x8*)&As[row * 64 + ((dg ^ (row & 7)) * 8)];
            }
#pragma unroll
            for (int nt = 0; nt < 4; ++nt) {
                const int row = wn + nt * 16 + fr, dg = half * 4 + qd;
                bfv[nt] = *(const bf16x8*)&Bs[row * 64 + ((dg ^ (row & 7)) * 8)];
            }
#pragma unroll
            for (int mt = 0; mt < 4; ++mt)
#pragma unroll
                for (int nt = 0; nt < 4; ++nt)
                    acc[mt][nt] = __builtin_amdgcn_mfma_f32_16x16x32_bf16(
                        af[mt], bfv[nt], acc[mt][nt], 0, 0, 0);
        }
        __syncthreads();
    }

#pragma unroll
    for (int mt = 0; mt < 4; ++mt) {
#pragma unroll
        for (int nt = 0; nt < 4; ++nt) {
            const int ncol = n0 + wn + nt * 16 + fr;
            const float bb = bo[ncol];
#pragma unroll
            for (int r = 0; r < 4; ++r) {
                const int mm = m0 + wm + mt * 16 + qd * 4 + r;
                out[(size_t)mm * C_ + ncol] = acc[mt][nt][r] + bb;
            }
        }
    }
}

// ---------------------------------------------------------------------------
// MFMA flash attention v5 — LDS-shared K/V tiles (unchanged, R8/R10-passing).
// ---------------------------------------------------------------------------
__global__ __launch_bounds__(256)
void attn_lds(const unsigned short* __restrict__ qb, const unsigned short* __restrict__ kb,
              const unsigned short* __restrict__ vtt, unsigned short* __restrict__ attb)
{
    __shared__ unsigned short Ks[64 * 64];
    __shared__ unsigned short Vs[64 * 64];
    __shared__ alignas(16) unsigned short Pt[4][16 * 72];

    const int tid = threadIdx.x;
    const int lane = tid & 63, w = tid >> 6;
    const int fr = lane & 15, qd = lane >> 4;

    const int blk = blockIdx.x;
    const int xcd = blk & 7, within = blk >> 3;      // within: 0..127
    const int bh = xcd * 4 + (within & 3);           // bh constant per CU slot
    const int jj = within >> 2;                      // 0..31
    const int kk_ = jj >> 3, ii_ = jj & 7;
    const int qt = (kk_ == 0) ? (31 - ii_) : (kk_ == 1) ? ii_
                 : (kk_ == 2) ? (23 - ii_) : (8 + ii_);
    const int b = bh >> 4, h = bh & 15;

    unsigned short* Pw = Pt[w];
    const unsigned short* qB = qb  + (size_t)bh * T_ * D_;
    const unsigned short* kB = kb  + (size_t)bh * T_ * D_;
    const unsigned short* vT = vtt + (size_t)bh * (T_ / 64) * 64 * 64;

    const int qr0 = qt * 64 + w * 16;
    const int qrow_g = qr0 + fr;

    bf16x8 aq0 = *(const bf16x8*)(qB + (size_t)(qr0 + fr) * D_ + qd * 8);
    bf16x8 aq1 = *(const bf16x8*)(qB + (size_t)(qr0 + fr) * D_ + 32 + qd * 8);

    f32x4 accT[4] = {};
    float l_i = 0.0f;
    const float sc2 = 0.18033688f;                   // log2(e) / sqrt(64)

    const int L0 = w * 128 + lane, L1 = L0 + 64;
    const int r0 = L0 >> 3, e0 = (((L0 & 7) ^ (r0 & 7)) * 8);
    const int r1 = L1 >> 3, e1 = (((L1 & 7) ^ (r1 & 7)) * 8);
    laddr_t* dK0 = (laddr_t*)((char*)Ks + (size_t)L0 * 16);
    laddr_t* dK1 = (laddr_t*)((char*)Ks + (size_t)L1 * 16);
    laddr_t* dV0 = (laddr_t*)((char*)Vs + (size_t)L0 * 16);
    laddr_t* dV1 = (laddr_t*)((char*)Vs + (size_t)L1 * 16);

    for (int jt = 0; jt <= qt; ++jt) {
        __syncthreads();
        {
            const unsigned short* kt = kB + (size_t)(jt * 64) * 64;
            const unsigned short* vt = vT + (size_t)jt * 4096;
            __builtin_amdgcn_global_load_lds((gaddr_t*)(kt + r0 * 64 + e0), dK0, 16, 0, 0);
            __builtin_amdgcn_global_load_lds((gaddr_t*)(kt + r1 * 64 + e1), dK1, 16, 0, 0);
            __builtin_amdgcn_global_load_lds((gaddr_t*)(vt + r0 * 64 + e0), dV0, 16, 0, 0);
            __builtin_amdgcn_global_load_lds((gaddr_t*)(vt + r1 * 64 + e1), dV1, 16, 0, 0);
        }
        __syncthreads();

        bf16x8 bk[8];
#pragma unroll
        for (int q8 = 0; q8 < 8; ++q8) {
            const int row = (q8 >> 1) * 16 + fr;
            const int dg = (q8 & 1) * 4 + qd;
            bk[q8] = *(const bf16x8*)&Ks[row * 64 + ((dg ^ (row & 7)) * 8)];
        }

        f32x4 s4[4] = {};
#pragma unroll
        for (int nt = 0; nt < 4; ++nt) {
            s4[nt] = __builtin_amdgcn_mfma_f32_16x16x32_bf16(bk[nt * 2 + 0], aq0, s4[nt], 0, 0, 0);
            s4[nt] = __builtin_amdgcn_mfma_f32_16x16x32_bf16(bk[nt * 2 + 1], aq1, s4[nt], 0, 0, 0);
        }

        if (jt == qt) {
            const int kbase = jt * 64 + qd * 4;
#pragma unroll
            for (int nt = 0; nt < 4; ++nt)
#pragma unroll
            for (int r = 0; r < 4; ++r) {
                const int kcol = kbase + nt * 16 + r;
                const float pv = (kcol <= qrow_g)
                               ? __builtin_amdgcn_exp2f(s4[nt][r] * sc2) : 0.0f;
                s4[nt][r] = pv;
                l_i += pv;
            }
        } else {
#pragma unroll
            for (int nt = 0; nt < 4; ++nt)
#pragma unroll
            for (int r = 0; r < 4; ++r) {
                const float pv = __builtin_amdgcn_exp2f(s4[nt][r] * sc2);
                s4[nt][r] = pv;
                l_i += pv;
            }
        }

#pragma unroll
        for (int nt = 0; nt < 4; ++nt) {
            union { __hip_bfloat162 h2[2]; unsigned long long u; } pk;
            pk.h2[0] = __float22bfloat162_rn(make_float2(s4[nt][0], s4[nt][1]));
            pk.h2[1] = __float22bfloat162_rn(make_float2(s4[nt][2], s4[nt][3]));
            *(unsigned long long*)&Pw[fr * 72 + nt * 16 + qd * 4] = pk.u;
        }
        const bf16x8 ap0 = *(const bf16x8*)&Pw[fr * 72 + qd * 8];
        const bf16x8 ap1 = *(const bf16x8*)&Pw[fr * 72 + 32 + qd * 8];

        bf16x8 bv[8];
#pragma unroll
        for (int q8 = 0; q8 < 8; ++q8) {
            const int row = (q8 >> 1) * 16 + fr;
            const int dg = (q8 & 1) * 4 + qd;
            bv[q8] = *(const bf16x8*)&Vs[row * 64 + ((dg ^ (row & 7)) * 8)];
        }

#pragma unroll
        for (int nt = 0; nt < 4; ++nt) {
            accT[nt] = __builtin_amdgcn_mfma_f32_16x16x32_bf16(bv[nt * 2 + 0], ap0, accT[nt], 0, 0, 0);
            accT[nt] = __builtin_amdgcn_mfma_f32_16x16x32_bf16(bv[nt * 2 + 1], ap1, accT[nt], 0, 0, 0);
        }
    }

    l_i += __shfl_xor(l_i, 16);
    l_i += __shfl_xor(l_i, 32);
    const float inv = 1.0f / l_i;

#pragma unroll
    for (int nt = 0; nt < 4; ++nt) {
        union { __hip_bfloat162 h2[2]; unsigned long long u; } ok;
        ok.h2[0] = __float22bfloat162_rn(make_float2(accT[nt][0] * inv, accT[nt][1] * inv));
        ok.h2[1] = __float22bfloat162_rn(make_float2(accT[nt][2] * inv, accT[nt][3] * inv));
        *(unsigned long long*)&Pw[fr * 72 + nt * 16 + qd * 4] = ok.u;
    }
    {
        const int row = lane >> 2, d0 = (lane & 3) * 16;
        const bf16x8 o0 = *(const bf16x8*)&Pw[row * 72 + d0];
        const bf16x8 o1 = *(const bf16x8*)&Pw[row * 72 + d0 + 8];
        unsigned short* op = attb + ((size_t)b * T_ + qr0 + row) * C_ + h * 64 + d0;
        *(bf16x8*)op = o0;
        *(bf16x8*)(op + 8) = o1;
    }
}

// ---------------------------------------------------------------------------
// Fallback (ws too small for kb): per-wave kernel, fp32 K + tiled V^T.
// ---------------------------------------------------------------------------
__global__ __launch_bounds__(256)
void attn_v4(const unsigned short* __restrict__ qb, const float* __restrict__ kf,
             const unsigned short* __restrict__ vtt, unsigned short* __restrict__ attb)
{
    __shared__ alignas(16) unsigned short Pt[4][16 * 72];

    const int tid = threadIdx.x;
    const int lane = tid & 63, w = tid >> 6;
    const int fr = lane & 15, qd = lane >> 4;

    const int blk = blockIdx.x;
    const int xcd = blk & 7, within = blk >> 3;
    const int bh = xcd * 4 + (within & 3);
    const int jj = within >> 2;
    const int kk_ = jj >> 3, ii_ = jj & 7;
    const int qt = (kk_ == 0) ? (31 - ii_) : (kk_ == 1) ? ii_
                 : (kk_ == 2) ? (23 - ii_) : (8 + ii_);
    const int b = bh >> 4, h = bh & 15;

    unsigned short* Pw = Pt[w];
    const unsigned short* qB = qb  + (size_t)bh * T_ * D_;
    const float*          kB = kf  + (size_t)bh * T_ * D_;
    const unsigned short* vT = vtt + (size_t)bh * (T_ / 64) * 64 * 64;

    const int qr0 = qt * 64 + w * 16;
    const int qrow_g = qr0 + fr;

    bf16x8 aq0 = *(const bf16x8*)(qB + (size_t)(qr0 + fr) * D_ + qd * 8);
    bf16x8 aq1 = *(const bf16x8*)(qB + (size_t)(qr0 + fr) * D_ + 32 + qd * 8);

    f32x4 accT[4] = {};
    float l_i = 0.0f;
    const float sc2 = 0.18033688f;

    for (int jt = 0; jt <= qt; ++jt) {
        bf16x8 bk[8];
#pragma unroll
        for (int q8 = 0; q8 < 8; ++q8) {
            const float* p = kB + (size_t)(jt * 64 + (q8 >> 1) * 16 + fr) * D_
                           + (q8 & 1) * 32 + qd * 8;
            bk[q8] = cvt8(*(const float4*)p, *(const float4*)(p + 4));
        }
        f32x4 s4[4] = {};
#pragma unroll
        for (int nt = 0; nt < 4; ++nt) {
            s4[nt] = __builtin_amdgcn_mfma_f32_16x16x32_bf16(bk[nt * 2 + 0], aq0, s4[nt], 0, 0, 0);
            s4[nt] = __builtin_amdgcn_mfma_f32_16x16x32_bf16(bk[nt * 2 + 1], aq1, s4[nt], 0, 0, 0);
        }
        if (jt == qt) {
            const int kbase = jt * 64 + qd * 4;
#pragma unroll
            for (int nt = 0; nt < 4; ++nt)
#pragma unroll
            for (int r = 0; r < 4; ++r) {
                const int kcol = kbase + nt * 16 + r;
                const float pv = (kcol <= qrow_g)
                               ? __builtin_amdgcn_exp2f(s4[nt][r] * sc2) : 0.0f;
                s4[nt][r] = pv; l_i += pv;
            }
        } else {
#pragma unroll
            for (int nt = 0; nt < 4; ++nt)
#pragma unroll
            for (int r = 0; r < 4; ++r) {
                const float pv = __builtin_amdgcn_exp2f(s4[nt][r] * sc2);
                s4[nt][r] = pv; l_i += pv;
            }
        }
#pragma unroll
        for (int nt = 0; nt < 4; ++nt) {
            union { __hip_bfloat162 h2[2]; unsigned long long u; } pk;
            pk.h2[0] = __float22bfloat162_rn(make_float2(s4[nt][0], s4[nt][1]));
            pk.h2[1] = __float22bfloat162_rn(make_float2(s4[nt][2], s4[nt][3]));
            *(unsigned long long*)&Pw[fr * 72 + nt * 16 + qd * 4] = pk.u;
        }
        const bf16x8 ap0 = *(const bf16x8*)&Pw[fr * 72 + qd * 8];
        const bf16x8 ap1 = *(const bf16x8*)&Pw[fr * 72 + 32 + qd * 8];

        bf16x8 bv[8];
#pragma unroll
        for (int q8 = 0; q8 < 8; ++q8)
            bv[q8] = *(const bf16x8*)(vT + (size_t)jt * 4096
                                      + ((q8 >> 1) * 16 + fr) * 64 + (q8 & 1) * 32 + qd * 8);
#pragma unroll
        for (int nt = 0; nt < 4; ++nt) {
            accT[nt] = __builtin_amdgcn_mfma_f32_16x16x32_bf16(bv[nt * 2 + 0], ap0, accT[nt], 0, 0, 0);
            accT[nt] = __builtin_amdgcn_mfma_f32_16x16x32_bf16(bv[nt * 2 + 1], ap1, accT[nt], 0, 0, 0);
        }
    }

    l_i += __shfl_xor(l_i, 16);
    l_i += __shfl_xor(l_i, 32);
    const float inv = 1.0f / l_i;
#pragma unroll
    for (int nt = 0; nt < 4; ++nt) {
        union { __hip_bfloat162 h2[2]; unsigned long long u; } ok;
        ok.h2[0] = __float22bfloat162_rn(make_float2(accT[nt][0] * inv, accT[nt][1] * inv));
        ok.h2[1] = __float22bfloat162_rn(make_float2(accT[nt][2] * inv, accT[nt][3] * inv));
        *(unsigned long long*)&Pw[fr * 72 + nt * 16 + qd * 4] = ok.u;
    }
    {
        const int row = lane >> 2, d0 = (lane & 3) * 16;
        const bf16x8 o0 = *(const bf16x8*)&Pw[row * 72 + d0];
        const bf16x8 o1 = *(const bf16x8*)&Pw[row * 72 + d0 + 8];
        unsigned short* op = attb + ((size_t)b * T_ + qr0 + row) * C_ + h * 64 + d0;
        *(bf16x8*)op = o0;
        *(bf16x8*)(op + 8) = o1;
    }
}

// ---------------------------------------------------------------------------
extern "C" void kernel_launch(void* const* d_in, const int* in_sizes, int n_in,
                              void* d_out, int out_size, void* d_ws, size_t ws_size,
                              hipStream_t stream)
{
    (void)in_sizes; (void)n_in; (void)out_size;
    const float* x  = (const float*)d_in[0];
    const float* Wq = (const float*)d_in[1];
    const float* Wk = (const float*)d_in[2];
    const float* Wv = (const float*)d_in[3];
    const float* Wo = (const float*)d_in[4];
    const float* bo = (const float*)d_in[5];

    float* out  = (float*)d_out;                       // (B,T,C)
    float* kout = out  + (size_t)M_ * C_;              // (B,H,T,D) fp32
    float* vout = kout + (size_t)B_ * H_ * T_ * D_;    // (B,H,T,D) fp32

    // ws: xb(8M) | wtb(8M) | qb(8M) | vtt(8M) | kb(8M, optional); attb aliases xb
    unsigned short* xb   = (unsigned short*)d_ws;
    unsigned short* wtb  = xb  + (size_t)M_ * C_;
    unsigned short* qb   = wtb + (size_t)4 * C_ * C_;
    unsigned short* vtt  = qb  + (size_t)M_ * C_;
    unsigned short* kb   = vtt + (size_t)M_ * C_;
    unsigned short* attb = xb;
    const bool use_kb = ws_size >= (size_t)40 * 1024 * 1024;

    cast_x<<<1024, 256, 0, stream>>>(x, xb, (M_ * C_) / 4);
    tcast_w<<<dim3(16, 16, 4), 256, 0, stream>>>(Wq, Wk, Wv, Wo, wtb);

    if (use_kb)
        gemm_qkv<1><<<dim3(24, M_ / 128), 256, 0, stream>>>(xb, wtb, qb, kout, vout, kb);
    else
        gemm_qkv<0><<<dim3(24, M_ / 128), 256, 0, stream>>>(xb, wtb, qb, kout, vout, kb);

    transpose_v<<<dim3(T_ / 64, B_ * H_), 256, 0, stream>>>(vout, vtt);

    if (use_kb)
        attn_lds<<<1024, 256, 0, stream>>>(qb, kb, vtt, attb);
    else
        attn_v4<<<1024, 256, 0, stream>>>(qb, kout, vtt, attb);

    gemm_o<<<dim3(8, M_ / 128), 256, 0, stream>>>(attb, wtb + (size_t)3 * C_ * C_, bo, out);
}